// Round 1
// baseline (1984.269 us; speedup 1.0000x reference)
//
#include <hip/hip_runtime.h>

#define HID 128
#define NG 512
#define NC 10

static __device__ __forceinline__ int gtid() {
    return blockIdx.x * blockDim.x + threadIdx.x;
}

__global__ void k_fill(float* __restrict__ p, float v, int n) {
    int i = gtid();
    if (i < n) p[i] = v;
}

// deg[dst] += 1 for each edge (deg buffer pre-filled with 1.0 for self-loops)
__global__ void k_degcount(const int* __restrict__ dst, float* __restrict__ deg, int E) {
    int i = gtid();
    if (i < E) atomicAdd(&deg[dst[i]], 1.0f);
}

__global__ void k_rsqrt(float* __restrict__ d, int n) {
    int i = gtid();
    if (i < n) d[i] = rsqrtf(d[i]);
}

// S[v] = dinv[v]^2 (self-loop norm)
__global__ void k_sinit(const float* __restrict__ dinv, float* __restrict__ S, int n) {
    int i = gtid();
    if (i < n) { float v = dinv[i]; S[i] = v * v; }
}

// norm[e] = dinv[src]*dinv[dst]; S[dst] += norm[e]
__global__ void k_sedges(const int* __restrict__ src, const int* __restrict__ dst,
                         const float* __restrict__ dinv, float* __restrict__ S,
                         float* __restrict__ norm, int E) {
    int i = gtid();
    if (i < E) {
        float nv = dinv[src[i]] * dinv[dst[i]];
        norm[i] = nv;
        atomicAdd(&S[dst[i]], nv);
    }
}

// layer 0: x[v,d] = relu(S[v]*W0[d] + b0[d])   (input features are all-ones, 1-dim)
__global__ void k_layer0(const float* __restrict__ S, const float* __restrict__ W0,
                         const float* __restrict__ b0, float* __restrict__ x, int n128) {
    int i = gtid();
    if (i < n128) {
        int d = i & (HID - 1);
        int v = i >> 7;
        x[i] = fmaxf(fmaf(S[v], W0[d], b0[d]), 0.0f);
    }
}

// y[N,128] = x[N,128] @ W[128,128]  (fp32, W staged in LDS, 4x4 register tile)
__global__ __launch_bounds__(256) void k_gemm(const float* __restrict__ x,
                                              const float* __restrict__ W,
                                              float* __restrict__ y, int nrows) {
    __shared__ float Wl[HID * HID];   // 64 KiB
    __shared__ float Xt[HID * 36];    // transposed x tile, padded stride 36
    int tid = threadIdx.x;

    for (int i = tid * 4; i < HID * HID; i += 256 * 4) {
        *(float4*)&Wl[i] = *(const float4*)&W[i];
    }
    int R0 = blockIdx.x * 32;
    for (int i = tid; i < 32 * HID; i += 256) {
        int r = i >> 7;        // 0..31
        int k = i & (HID - 1); // 0..127
        int row = R0 + r;
        Xt[k * 36 + r] = (row < nrows) ? x[(size_t)row * HID + k] : 0.0f;
    }
    __syncthreads();

    int tc = tid & 31;   // col group
    int tr = tid >> 5;   // row group (0..7)
    int c0 = tc * 4;
    int r0 = tr * 4;
    float acc[4][4] = {};
    for (int k = 0; k < HID; ++k) {
        float4 wv = *(float4*)&Wl[k * HID + c0];
        float4 xv = *(float4*)&Xt[k * 36 + r0];
        float xr[4] = {xv.x, xv.y, xv.z, xv.w};
        float wc[4] = {wv.x, wv.y, wv.z, wv.w};
#pragma unroll
        for (int i = 0; i < 4; ++i)
#pragma unroll
            for (int j = 0; j < 4; ++j)
                acc[i][j] = fmaf(xr[i], wc[j], acc[i][j]);
    }
#pragma unroll
    for (int i = 0; i < 4; ++i) {
        int row = R0 + r0 + i;
        if (row < nrows) {
            float4 o;
            o.x = acc[i][0]; o.y = acc[i][1]; o.z = acc[i][2]; o.w = acc[i][3];
            *(float4*)&y[(size_t)row * HID + c0] = o;
        }
    }
}

// y[v,:] = h[v,:]*dinv[v]^2 + b   (self-loop message + bias; init for scatter accumulation)
__global__ void k_selfinit(const float* __restrict__ h, const float* __restrict__ dinv,
                           const float* __restrict__ b, float* __restrict__ y, int n128) {
    int i = gtid();
    if (i < n128) {
        int v = i >> 7;
        int d = i & (HID - 1);
        float di = dinv[v];
        y[i] = fmaf(h[i], di * di, b[d]);
    }
}

// y[dst,:] += h[src,:] * norm[e]   (128 threads per edge)
__global__ void k_scatter(const int* __restrict__ src, const int* __restrict__ dst,
                          const float* __restrict__ norm, const float* __restrict__ h,
                          float* __restrict__ y, int E) {
    int idx = gtid();
    int e = idx >> 7;
    int d = idx & (HID - 1);
    if (e < E) {
        int s = src[e];
        int t = dst[e];
        float nv = norm[e];
        atomicAdd(&y[(size_t)t * HID + d], h[(size_t)s * HID + d] * nv);
    }
}

__global__ void k_relu(float* __restrict__ y, int n) {
    int i = gtid();
    if (i < n) y[i] = fmaxf(y[i], 0.0f);
}

// segment-sum pooling over sorted batch; chunked local accumulation to cut atomics
__global__ void k_pool(const float* __restrict__ x, const int* __restrict__ batch,
                       float* __restrict__ pooled, float* __restrict__ cnt, int N) {
    const int K = 32;
    int d = threadIdx.x & (HID - 1);
    int chunk = blockIdx.x * 2 + (threadIdx.x >> 7);
    int v0 = chunk * K;
    if (v0 >= N) return;
    int vend = v0 + K; if (vend > N) vend = N;
    int g = batch[v0];
    float acc = 0.0f, c = 0.0f;
    for (int v = v0; v < vend; ++v) {
        int gv = batch[v];
        if (gv != g) {
            atomicAdd(&pooled[g * HID + d], acc);
            if (d == 0) atomicAdd(&cnt[g], c);
            acc = 0.0f; c = 0.0f; g = gv;
        }
        acc += x[(size_t)v * HID + d];
        c += 1.0f;
    }
    atomicAdd(&pooled[g * HID + d], acc);
    if (d == 0) atomicAdd(&cnt[g], c);
}

// logits = pooled/cnt @ Wp + bp, then log_softmax. One thread per graph.
__global__ void k_head(const float* __restrict__ pooled, const float* __restrict__ cnt,
                       const float* __restrict__ Wp, const float* __restrict__ bp,
                       float* __restrict__ out) {
    int g = gtid();
    if (g >= NG) return;
    float inv = 1.0f / fmaxf(cnt[g], 1.0f);
    float l[NC];
#pragma unroll
    for (int c = 0; c < NC; ++c) l[c] = bp[c];
    for (int d = 0; d < HID; ++d) {
        float pv = pooled[g * HID + d] * inv;
#pragma unroll
        for (int c = 0; c < NC; ++c) l[c] = fmaf(pv, Wp[d * NC + c], l[c]);
    }
    float m = l[0];
#pragma unroll
    for (int c = 1; c < NC; ++c) m = fmaxf(m, l[c]);
    float s = 0.0f;
#pragma unroll
    for (int c = 0; c < NC; ++c) s += expf(l[c] - m);
    float ls = logf(s) + m;
#pragma unroll
    for (int c = 0; c < NC; ++c) out[g * NC + c] = l[c] - ls;
}

extern "C" void kernel_launch(void* const* d_in, const int* in_sizes, int n_in,
                              void* d_out, int out_size, void* d_ws, size_t ws_size,
                              hipStream_t stream) {
    const int* ei    = (const int*)d_in[0];
    int E            = in_sizes[0] / 2;
    const int* src   = ei;
    const int* dstp  = ei + E;
    const int* batch = (const int*)d_in[1];
    int N            = in_sizes[1];
    const float* W0  = (const float*)d_in[2];
    const float* b0  = (const float*)d_in[3];
    const float* W1  = (const float*)d_in[4];
    const float* b1  = (const float*)d_in[5];
    const float* W2  = (const float*)d_in[6];
    const float* b2  = (const float*)d_in[7];
    const float* Wp  = (const float*)d_in[8];
    const float* bp  = (const float*)d_in[9];
    float* out       = (float*)d_out;

    float* ws     = (float*)d_ws;
    float* dinv   = ws;                        // N
    float* S      = dinv + N;                  // N
    float* norm   = S + N;                     // E
    float* xA     = norm + E;                  // N*HID
    float* xB     = xA + (size_t)N * HID;      // N*HID
    float* pooled = xB + (size_t)N * HID;      // NG*HID
    float* cnt    = pooled + NG * HID;         // NG

    int n128 = N * HID;
    auto cdiv = [](int a, int b) { return (a + b - 1) / b; };

    // init
    k_fill<<<cdiv(NG * HID + NG, 256), 256, 0, stream>>>(pooled, 0.0f, NG * HID + NG);
    k_fill<<<cdiv(N, 256), 256, 0, stream>>>(dinv, 1.0f, N);

    // degree + normalization
    k_degcount<<<cdiv(E, 256), 256, 0, stream>>>(dstp, dinv, E);
    k_rsqrt<<<cdiv(N, 256), 256, 0, stream>>>(dinv, N);
    k_sinit<<<cdiv(N, 256), 256, 0, stream>>>(dinv, S, N);
    k_sedges<<<cdiv(E, 256), 256, 0, stream>>>(src, dstp, dinv, S, norm, E);

    // layer 0 (rank-1 shortcut)
    k_layer0<<<cdiv(n128, 256), 256, 0, stream>>>(S, W0, b0, xA, n128);

    // layer 1
    k_gemm<<<cdiv(N, 32), 256, 0, stream>>>(xA, W1, xB, N);
    k_selfinit<<<cdiv(n128, 256), 256, 0, stream>>>(xB, dinv, b1, xA, n128);
    k_scatter<<<cdiv(E * HID, 256), 256, 0, stream>>>(src, dstp, norm, xB, xA, E);
    k_relu<<<cdiv(n128, 256), 256, 0, stream>>>(xA, n128);

    // layer 2
    k_gemm<<<cdiv(N, 32), 256, 0, stream>>>(xA, W2, xB, N);
    k_selfinit<<<cdiv(n128, 256), 256, 0, stream>>>(xB, dinv, b2, xA, n128);
    k_scatter<<<cdiv(E * HID, 256), 256, 0, stream>>>(src, dstp, norm, xB, xA, E);
    k_relu<<<cdiv(n128, 256), 256, 0, stream>>>(xA, n128);

    // pooling + head
    k_pool<<<cdiv(cdiv(N, 32), 2), 256, 0, stream>>>(xA, batch, pooled, cnt, N);
    k_head<<<2, 256, 0, stream>>>(pooled, cnt, Wp, bp, out);
}

// Round 2
// 922.011 us; speedup vs baseline: 2.1521x; 2.1521x over previous
//
#include <hip/hip_runtime.h>

#define HID 128
#define NG 512
#define NC 10

static __device__ __forceinline__ int gtid() {
    return blockIdx.x * blockDim.x + threadIdx.x;
}

// in-degree histogram (real edges only)
__global__ void k_hist(const int* __restrict__ dst, int* __restrict__ cnt, int E) {
    int i = gtid();
    if (i < E) atomicAdd(&cnt[dst[i]], 1);
}

// exclusive prefix sum over cnt[0..N) -> rowptr[0..N]; single block of 1024
__global__ __launch_bounds__(1024) void k_scan(const int* __restrict__ cnt,
                                               int* __restrict__ rowptr, int N) {
    __shared__ int s[1024];
    int tid = threadIdx.x;
    int chunk = (N + 1023) >> 10;
    int start = tid * chunk;
    int end = start + chunk; if (end > N) end = N;
    int sum = 0;
    for (int i = start; i < end; ++i) sum += cnt[i];
    s[tid] = sum;
    __syncthreads();
    for (int off = 1; off < 1024; off <<= 1) {
        int v = (tid >= off) ? s[tid - off] : 0;
        __syncthreads();
        s[tid] += v;
        __syncthreads();
    }
    int run = (tid > 0) ? s[tid - 1] : 0;
    for (int i = start; i < end; ++i) { rowptr[i] = run; run += cnt[i]; }
    if (tid == 1023) rowptr[N] = s[1023];
}

// dinv[v] = rsqrt(deg) with deg = indeg + 1 (self-loop)
__global__ void k_dinv(const int* __restrict__ cnt, float* __restrict__ dinv, int N) {
    int i = gtid();
    if (i < N) dinv[i] = rsqrtf(1.0f + (float)cnt[i]);
}

// scatter edges into CSR slots: packed[pos] = {src, norm}
__global__ void k_fillcsr(const int* __restrict__ src, const int* __restrict__ dst,
                          const float* __restrict__ dinv, int* __restrict__ cursor,
                          int2* __restrict__ packed, int E) {
    int e = gtid();
    if (e < E) {
        int t = dst[e], s = src[e];
        int pos = atomicAdd(&cursor[t], 1);
        packed[pos] = make_int2(s, __float_as_int(dinv[s] * dinv[t]));
    }
}

// S[v] = dinv[v]^2 + sum of incoming norms  (for the rank-1 layer-0 shortcut)
__global__ void k_S(const int* __restrict__ rowptr, const int2* __restrict__ packed,
                    const float* __restrict__ dinv, float* __restrict__ S, int N) {
    int v = gtid();
    if (v < N) {
        float di = dinv[v];
        float s = di * di;
        int r1 = rowptr[v + 1];
        for (int j = rowptr[v]; j < r1; ++j) s += __int_as_float(packed[j].y);
        S[v] = s;
    }
}

// layer 0: x[v,d] = relu(S[v]*W0[d] + b0[d])   (input features are all-ones, 1-dim)
__global__ void k_layer0(const float* __restrict__ S, const float* __restrict__ W0,
                         const float* __restrict__ b0, float* __restrict__ x, int n128) {
    int i = gtid();
    if (i < n128) {
        int d = i & (HID - 1);
        int v = i >> 7;
        x[i] = fmaxf(fmaf(S[v], W0[d], b0[d]), 0.0f);
    }
}

// y[N,128] = x[N,128] @ W[128,128]  (fp32, W staged in LDS, 4x4 register tile)
__global__ __launch_bounds__(256) void k_gemm(const float* __restrict__ x,
                                              const float* __restrict__ W,
                                              float* __restrict__ y, int nrows) {
    __shared__ float Wl[HID * HID];   // 64 KiB
    __shared__ float Xt[HID * 36];    // transposed x tile, padded stride 36
    int tid = threadIdx.x;

    for (int i = tid * 4; i < HID * HID; i += 256 * 4) {
        *(float4*)&Wl[i] = *(const float4*)&W[i];
    }
    int R0 = blockIdx.x * 32;
    for (int i = tid; i < 32 * HID; i += 256) {
        int r = i >> 7;
        int k = i & (HID - 1);
        int row = R0 + r;
        Xt[k * 36 + r] = (row < nrows) ? x[(size_t)row * HID + k] : 0.0f;
    }
    __syncthreads();

    int tc = tid & 31;
    int tr = tid >> 5;
    int c0 = tc * 4;
    int r0 = tr * 4;
    float acc[4][4] = {};
    for (int k = 0; k < HID; ++k) {
        float4 wv = *(float4*)&Wl[k * HID + c0];
        float4 xv = *(float4*)&Xt[k * 36 + r0];
        float xr[4] = {xv.x, xv.y, xv.z, xv.w};
        float wc[4] = {wv.x, wv.y, wv.z, wv.w};
#pragma unroll
        for (int i = 0; i < 4; ++i)
#pragma unroll
            for (int j = 0; j < 4; ++j)
                acc[i][j] = fmaf(xr[i], wc[j], acc[i][j]);
    }
#pragma unroll
    for (int i = 0; i < 4; ++i) {
        int row = R0 + r0 + i;
        if (row < nrows) {
            float4 o;
            o.x = acc[i][0]; o.y = acc[i][1]; o.z = acc[i][2]; o.w = acc[i][3];
            *(float4*)&y[(size_t)row * HID + c0] = o;
        }
    }
}

// fused aggregation: y[v,:] = relu( h[v,:]*dinv[v]^2 + b + sum_e norm[e]*h[src[e],:] )
// 32 lanes per node, each lane owns 4 dims (float4); edges streamed in chunks of 32
__global__ __launch_bounds__(256) void k_aggr(const int2* __restrict__ packed,
                                              const int* __restrict__ rowptr,
                                              const float* __restrict__ h,
                                              const float* __restrict__ dinv,
                                              const float* __restrict__ b,
                                              float* __restrict__ y, int N) {
    int lane = threadIdx.x & 31;
    int v = (blockIdx.x * 256 + threadIdx.x) >> 5;
    if (v >= N) return;
    int r0 = rowptr[v], r1 = rowptr[v + 1];
    float di = dinv[v];
    float d2 = di * di;
    int d0 = lane * 4;
    float4 hv = *(const float4*)&h[(size_t)v * HID + d0];
    float4 bv = *(const float4*)&b[d0];
    float4 acc;
    acc.x = fmaf(hv.x, d2, bv.x);
    acc.y = fmaf(hv.y, d2, bv.y);
    acc.z = fmaf(hv.z, d2, bv.z);
    acc.w = fmaf(hv.w, d2, bv.w);
    for (int base = r0; base < r1; base += 32) {
        int2 pk = (base + lane < r1) ? packed[base + lane] : make_int2(0, 0);
        int m = r1 - base; if (m > 32) m = 32;
        for (int k = 0; k < m; ++k) {
            int s = __shfl(pk.x, k, 32);
            float nv = __shfl(__int_as_float(pk.y), k, 32);
            float4 hs = *(const float4*)&h[(size_t)s * HID + d0];
            acc.x = fmaf(hs.x, nv, acc.x);
            acc.y = fmaf(hs.y, nv, acc.y);
            acc.z = fmaf(hs.z, nv, acc.z);
            acc.w = fmaf(hs.w, nv, acc.w);
        }
    }
    acc.x = fmaxf(acc.x, 0.0f);
    acc.y = fmaxf(acc.y, 0.0f);
    acc.z = fmaxf(acc.z, 0.0f);
    acc.w = fmaxf(acc.w, 0.0f);
    *(float4*)&y[(size_t)v * HID + d0] = acc;
}

// segment-sum pooling over sorted batch; chunked local accumulation to cut atomics
__global__ void k_pool(const float* __restrict__ x, const int* __restrict__ batch,
                       float* __restrict__ pooled, float* __restrict__ cnt, int N) {
    const int K = 32;
    int d = threadIdx.x & (HID - 1);
    int chunk = blockIdx.x * 2 + (threadIdx.x >> 7);
    int v0 = chunk * K;
    if (v0 >= N) return;
    int vend = v0 + K; if (vend > N) vend = N;
    int g = batch[v0];
    float acc = 0.0f, c = 0.0f;
    for (int v = v0; v < vend; ++v) {
        int gv = batch[v];
        if (gv != g) {
            atomicAdd(&pooled[g * HID + d], acc);
            if (d == 0) atomicAdd(&cnt[g], c);
            acc = 0.0f; c = 0.0f; g = gv;
        }
        acc += x[(size_t)v * HID + d];
        c += 1.0f;
    }
    atomicAdd(&pooled[g * HID + d], acc);
    if (d == 0) atomicAdd(&cnt[g], c);
}

// logits = pooled/cnt @ Wp + bp, then log_softmax. One thread per graph.
__global__ void k_head(const float* __restrict__ pooled, const float* __restrict__ cnt,
                       const float* __restrict__ Wp, const float* __restrict__ bp,
                       float* __restrict__ out) {
    int g = gtid();
    if (g >= NG) return;
    float inv = 1.0f / fmaxf(cnt[g], 1.0f);
    float l[NC];
#pragma unroll
    for (int c = 0; c < NC; ++c) l[c] = bp[c];
    for (int d = 0; d < HID; ++d) {
        float pv = pooled[g * HID + d] * inv;
#pragma unroll
        for (int c = 0; c < NC; ++c) l[c] = fmaf(pv, Wp[d * NC + c], l[c]);
    }
    float m = l[0];
#pragma unroll
    for (int c = 1; c < NC; ++c) m = fmaxf(m, l[c]);
    float s = 0.0f;
#pragma unroll
    for (int c = 0; c < NC; ++c) s += expf(l[c] - m);
    float ls = logf(s) + m;
#pragma unroll
    for (int c = 0; c < NC; ++c) out[g * NC + c] = l[c] - ls;
}

extern "C" void kernel_launch(void* const* d_in, const int* in_sizes, int n_in,
                              void* d_out, int out_size, void* d_ws, size_t ws_size,
                              hipStream_t stream) {
    const int* ei    = (const int*)d_in[0];
    int E            = in_sizes[0] / 2;
    const int* src   = ei;
    const int* dstp  = ei + E;
    const int* batch = (const int*)d_in[1];
    int N            = in_sizes[1];
    const float* W0  = (const float*)d_in[2];
    const float* b0  = (const float*)d_in[3];
    const float* W1  = (const float*)d_in[4];
    const float* b1  = (const float*)d_in[5];
    const float* W2  = (const float*)d_in[6];
    const float* b2  = (const float*)d_in[7];
    const float* Wp  = (const float*)d_in[8];
    const float* bp  = (const float*)d_in[9];
    float* out       = (float*)d_out;

    // workspace layout (xA first for float4/int2 alignment; N*HID is even)
    float* ws     = (float*)d_ws;
    float* xA     = ws;                          // N*HID f
    float* xB     = xA + (size_t)N * HID;        // N*HID f
    int2*  packed = (int2*)(xB + (size_t)N * HID); // E int2
    int*   cnt_i  = (int*)(packed + E);          // N int
    int*   rowptr = cnt_i + N;                   // N+1 int
    int*   cursor = rowptr + N + 1;              // N int
    float* dinv   = (float*)(cursor + N);        // N f
    float* S      = dinv + N;                    // N f
    float* pooled = S + N;                       // NG*HID f
    float* cntg   = pooled + NG * HID;           // NG f

    int n128 = N * HID;
    auto cdiv = [](int a, int b) { return (a + b - 1) / b; };

    hipMemsetAsync(cnt_i, 0, N * sizeof(int), stream);
    hipMemsetAsync(pooled, 0, (NG * HID + NG) * sizeof(float), stream);

    // CSR build + normalization
    k_hist<<<cdiv(E, 256), 256, 0, stream>>>(dstp, cnt_i, E);
    k_scan<<<1, 1024, 0, stream>>>(cnt_i, rowptr, N);
    k_dinv<<<cdiv(N, 256), 256, 0, stream>>>(cnt_i, dinv, N);
    hipMemcpyAsync(cursor, rowptr, N * sizeof(int), hipMemcpyDeviceToDevice, stream);
    k_fillcsr<<<cdiv(E, 256), 256, 0, stream>>>(src, dstp, dinv, cursor, packed, E);
    k_S<<<cdiv(N, 256), 256, 0, stream>>>(rowptr, packed, dinv, S, N);

    // layer 0 (rank-1 shortcut)
    k_layer0<<<cdiv(n128, 256), 256, 0, stream>>>(S, W0, b0, xA, n128);

    // layer 1
    k_gemm<<<cdiv(N, 32), 256, 0, stream>>>(xA, W1, xB, N);
    k_aggr<<<cdiv(N, 8), 256, 0, stream>>>(packed, rowptr, xB, dinv, b1, xA, N);

    // layer 2
    k_gemm<<<cdiv(N, 32), 256, 0, stream>>>(xA, W2, xB, N);
    k_aggr<<<cdiv(N, 8), 256, 0, stream>>>(packed, rowptr, xB, dinv, b2, xA, N);

    // pooling + head
    k_pool<<<cdiv(cdiv(N, 32), 2), 256, 0, stream>>>(xA, batch, pooled, cntg, N);
    k_head<<<2, 256, 0, stream>>>(pooled, cntg, Wp, bp, out);
}

// Round 3
// 578.443 us; speedup vs baseline: 3.4304x; 1.5940x over previous
//
#include <hip/hip_runtime.h>

#define HID 128
#define NG 512
#define NC 10
#define SCHUNK 512

typedef unsigned int u32;
typedef unsigned short u16;

static __device__ __forceinline__ int gtid() {
    return blockIdx.x * blockDim.x + threadIdx.x;
}

// bf16 helpers (RNE pack, exact unpack); no header-struct dependence
static __device__ __forceinline__ u16 f2bf(float f) {
    u32 u = __float_as_uint(f);
    u32 r = u + 0x7fffu + ((u >> 16) & 1u);
    return (u16)(r >> 16);
}
static __device__ __forceinline__ float bf2f(u32 s) {
    return __uint_as_float(s << 16);
}

// ---------- CSR build ----------

__global__ void k_hist(const int* __restrict__ dst, int* __restrict__ cnt, int E) {
    int i = gtid();
    if (i < E) atomicAdd(&cnt[dst[i]], 1);
}

// per-block partial sums over chunks of SCHUNK
__global__ __launch_bounds__(256) void k_scan1(const int* __restrict__ cnt,
                                               int* __restrict__ partial, int N) {
    __shared__ int s[256];
    int t = threadIdx.x;
    int i0 = blockIdx.x * SCHUNK + t * 2;
    int v = 0;
    if (i0 < N) v += cnt[i0];
    if (i0 + 1 < N) v += cnt[i0 + 1];
    s[t] = v;
    __syncthreads();
    for (int off = 128; off > 0; off >>= 1) {
        if (t < off) s[t] += s[t + off];
        __syncthreads();
    }
    if (t == 0) partial[blockIdx.x] = s[0];
}

// exclusive scan of partials (B <= 256), single block
__global__ __launch_bounds__(256) void k_scan2(int* __restrict__ partial, int B) {
    __shared__ int s[256];
    int t = threadIdx.x;
    int own = (t < B) ? partial[t] : 0;
    s[t] = own;
    __syncthreads();
    for (int off = 1; off < 256; off <<= 1) {
        int v = (t >= off) ? s[t - off] : 0;
        __syncthreads();
        s[t] += v;
        __syncthreads();
    }
    if (t < B) partial[t] = s[t] - own;  // exclusive
}

// apply offsets -> rowptr; fuse dinv = rsqrt(1+indeg)
__global__ __launch_bounds__(256) void k_scan3(const int* __restrict__ cnt,
                                               const int* __restrict__ partial,
                                               int* __restrict__ rowptr,
                                               float* __restrict__ dinv, int N) {
    __shared__ int s[256];
    int t = threadIdx.x;
    int i0 = blockIdx.x * SCHUNK + t * 2;
    int c0 = 0, c1 = 0;
    if (i0 < N) c0 = cnt[i0];
    if (i0 + 1 < N) c1 = cnt[i0 + 1];
    int own = c0 + c1;
    s[t] = own;
    __syncthreads();
    for (int off = 1; off < 256; off <<= 1) {
        int v = (t >= off) ? s[t - off] : 0;
        __syncthreads();
        s[t] += v;
        __syncthreads();
    }
    int base = partial[blockIdx.x] + s[t] - own;
    if (i0 < N) { rowptr[i0] = base; dinv[i0] = rsqrtf(1.0f + (float)c0); }
    if (i0 + 1 < N) { rowptr[i0 + 1] = base + c0; dinv[i0 + 1] = rsqrtf(1.0f + (float)c1); }
    if (i0 >= N - 2 && i0 < N) rowptr[N] = base + own;  // last element writes total
}

// scatter edges into CSR slots: packed[pos] = {src, norm}
__global__ void k_fillcsr(const int* __restrict__ src, const int* __restrict__ dst,
                          const float* __restrict__ dinv, int* __restrict__ cursor,
                          int2* __restrict__ packed, int E) {
    int e = gtid();
    if (e < E) {
        int t = dst[e], s = src[e];
        int pos = atomicAdd(&cursor[t], 1);
        packed[pos] = make_int2(s, __float_as_int(dinv[s] * dinv[t]));
    }
}

// ---------- layer 0 (rank-1 shortcut), fused S-reduction + elementwise ----------
// warp of 32 lanes per node: reduce incoming norms, then x[v,:] = relu(S*W0 + b0) in bf16
__global__ __launch_bounds__(256) void k_sl0(const int* __restrict__ rowptr,
                                             const int2* __restrict__ packed,
                                             const float* __restrict__ dinv,
                                             const float* __restrict__ W0,
                                             const float* __restrict__ b0,
                                             u16* __restrict__ x, int N) {
    int lane = threadIdx.x & 31;
    int v = (blockIdx.x * 256 + threadIdx.x) >> 5;
    if (v >= N) return;
    int r0 = rowptr[v], r1 = rowptr[v + 1];
    float s = 0.0f;
    for (int j = r0 + lane; j < r1; j += 32) s += __int_as_float(packed[j].y);
#pragma unroll
    for (int off = 16; off > 0; off >>= 1) s += __shfl_xor(s, off, 32);
    float di = dinv[v];
    s += di * di;
    int d0 = lane * 4;
    float4 w = *(const float4*)&W0[d0];
    float4 b = *(const float4*)&b0[d0];
    float a0 = fmaxf(fmaf(s, w.x, b.x), 0.0f);
    float a1 = fmaxf(fmaf(s, w.y, b.y), 0.0f);
    float a2 = fmaxf(fmaf(s, w.z, b.z), 0.0f);
    float a3 = fmaxf(fmaf(s, w.w, b.w), 0.0f);
    uint2 o;
    o.x = (u32)f2bf(a0) | ((u32)f2bf(a1) << 16);
    o.y = (u32)f2bf(a2) | ((u32)f2bf(a3) << 16);
    *(uint2*)&x[(size_t)v * HID + d0] = o;
}

// ---------- GEMM: y[N,128] = x[N,128] @ W[128,128]; bf16 in/out, fp32 compute ----------
__global__ __launch_bounds__(256) void k_gemm(const u16* __restrict__ x,
                                              const float* __restrict__ W,
                                              u16* __restrict__ y, int nrows) {
    __shared__ float Wl[HID * HID];   // 64 KiB
    __shared__ float Xt[HID * 36];    // transposed x tile, padded stride 36
    int tid = threadIdx.x;

    for (int i = tid * 4; i < HID * HID; i += 256 * 4) {
        *(float4*)&Wl[i] = *(const float4*)&W[i];
    }
    int R0 = blockIdx.x * 32;
    for (int i = tid * 4; i < 32 * HID; i += 256 * 4) {
        int r = i >> 7;
        int k = i & (HID - 1);     // multiple of 4
        int row = R0 + r;
        uint2 u = make_uint2(0u, 0u);
        if (row < nrows) u = *(const uint2*)&x[(size_t)row * HID + k];
        Xt[(k + 0) * 36 + r] = bf2f(u.x & 0xffffu);
        Xt[(k + 1) * 36 + r] = bf2f(u.x >> 16);
        Xt[(k + 2) * 36 + r] = bf2f(u.y & 0xffffu);
        Xt[(k + 3) * 36 + r] = bf2f(u.y >> 16);
    }
    __syncthreads();

    int tc = tid & 31;
    int tr = tid >> 5;
    int c0 = tc * 4;
    int r0 = tr * 4;
    float acc[4][4] = {};
    for (int k = 0; k < HID; ++k) {
        float4 wv = *(float4*)&Wl[k * HID + c0];
        float4 xv = *(float4*)&Xt[k * 36 + r0];
        float xr[4] = {xv.x, xv.y, xv.z, xv.w};
        float wc[4] = {wv.x, wv.y, wv.z, wv.w};
#pragma unroll
        for (int i = 0; i < 4; ++i)
#pragma unroll
            for (int j = 0; j < 4; ++j)
                acc[i][j] = fmaf(xr[i], wc[j], acc[i][j]);
    }
#pragma unroll
    for (int i = 0; i < 4; ++i) {
        int row = R0 + r0 + i;
        if (row < nrows) {
            uint2 o;
            o.x = (u32)f2bf(acc[i][0]) | ((u32)f2bf(acc[i][1]) << 16);
            o.y = (u32)f2bf(acc[i][2]) | ((u32)f2bf(acc[i][3]) << 16);
            *(uint2*)&y[(size_t)row * HID + c0] = o;
        }
    }
}

// ---------- fused aggregation ----------
// y[v,:] = relu( h[v,:]*dinv[v]^2 + b + sum_e norm[e]*h[src[e],:] ); bf16 h/y, fp32 acc
__global__ __launch_bounds__(256) void k_aggr(const int2* __restrict__ packed,
                                              const int* __restrict__ rowptr,
                                              const u16* __restrict__ h,
                                              const float* __restrict__ dinv,
                                              const float* __restrict__ b,
                                              u16* __restrict__ y, int N) {
    int lane = threadIdx.x & 31;
    int v = (blockIdx.x * 256 + threadIdx.x) >> 5;
    if (v >= N) return;
    int r0 = rowptr[v], r1 = rowptr[v + 1];
    float di = dinv[v];
    float d2 = di * di;
    int d0 = lane * 4;
    uint2 hu = *(const uint2*)&h[(size_t)v * HID + d0];
    float4 bv = *(const float4*)&b[d0];
    float a0 = fmaf(bf2f(hu.x & 0xffffu), d2, bv.x);
    float a1 = fmaf(bf2f(hu.x >> 16),     d2, bv.y);
    float a2 = fmaf(bf2f(hu.y & 0xffffu), d2, bv.z);
    float a3 = fmaf(bf2f(hu.y >> 16),     d2, bv.w);
    for (int base = r0; base < r1; base += 32) {
        int2 pk = (base + lane < r1) ? packed[base + lane] : make_int2(0, 0);
        int m = r1 - base; if (m > 32) m = 32;
        for (int k = 0; k < m; ++k) {
            int s = __shfl(pk.x, k, 32);
            float nv = __shfl(__int_as_float(pk.y), k, 32);
            uint2 hs = *(const uint2*)&h[(size_t)s * HID + d0];
            a0 = fmaf(bf2f(hs.x & 0xffffu), nv, a0);
            a1 = fmaf(bf2f(hs.x >> 16),     nv, a1);
            a2 = fmaf(bf2f(hs.y & 0xffffu), nv, a2);
            a3 = fmaf(bf2f(hs.y >> 16),     nv, a3);
        }
    }
    uint2 o;
    o.x = (u32)f2bf(fmaxf(a0, 0.0f)) | ((u32)f2bf(fmaxf(a1, 0.0f)) << 16);
    o.y = (u32)f2bf(fmaxf(a2, 0.0f)) | ((u32)f2bf(fmaxf(a3, 0.0f)) << 16);
    *(uint2*)&y[(size_t)v * HID + d0] = o;
}

// ---------- pooling + head ----------

__global__ void k_pool(const u16* __restrict__ x, const int* __restrict__ batch,
                       float* __restrict__ pooled, float* __restrict__ cnt, int N) {
    const int K = 32;
    int d = threadIdx.x & (HID - 1);
    int chunk = blockIdx.x * 2 + (threadIdx.x >> 7);
    int v0 = chunk * K;
    if (v0 >= N) return;
    int vend = v0 + K; if (vend > N) vend = N;
    int g = batch[v0];
    float acc = 0.0f, c = 0.0f;
    for (int v = v0; v < vend; ++v) {
        int gv = batch[v];
        if (gv != g) {
            atomicAdd(&pooled[g * HID + d], acc);
            if (d == 0) atomicAdd(&cnt[g], c);
            acc = 0.0f; c = 0.0f; g = gv;
        }
        acc += bf2f((u32)x[(size_t)v * HID + d]);
        c += 1.0f;
    }
    atomicAdd(&pooled[g * HID + d], acc);
    if (d == 0) atomicAdd(&cnt[g], c);
}

__global__ void k_head(const float* __restrict__ pooled, const float* __restrict__ cnt,
                       const float* __restrict__ Wp, const float* __restrict__ bp,
                       float* __restrict__ out) {
    int g = gtid();
    if (g >= NG) return;
    float inv = 1.0f / fmaxf(cnt[g], 1.0f);
    float l[NC];
#pragma unroll
    for (int c = 0; c < NC; ++c) l[c] = bp[c];
    for (int d = 0; d < HID; ++d) {
        float pv = pooled[g * HID + d] * inv;
#pragma unroll
        for (int c = 0; c < NC; ++c) l[c] = fmaf(pv, Wp[d * NC + c], l[c]);
    }
    float m = l[0];
#pragma unroll
    for (int c = 1; c < NC; ++c) m = fmaxf(m, l[c]);
    float s = 0.0f;
#pragma unroll
    for (int c = 0; c < NC; ++c) s += expf(l[c] - m);
    float ls = logf(s) + m;
#pragma unroll
    for (int c = 0; c < NC; ++c) out[g * NC + c] = l[c] - ls;
}

extern "C" void kernel_launch(void* const* d_in, const int* in_sizes, int n_in,
                              void* d_out, int out_size, void* d_ws, size_t ws_size,
                              hipStream_t stream) {
    const int* ei    = (const int*)d_in[0];
    int E            = in_sizes[0] / 2;
    const int* src   = ei;
    const int* dstp  = ei + E;
    const int* batch = (const int*)d_in[1];
    int N            = in_sizes[1];
    const float* W0  = (const float*)d_in[2];
    const float* b0  = (const float*)d_in[3];
    const float* W1  = (const float*)d_in[4];
    const float* b1  = (const float*)d_in[5];
    const float* W2  = (const float*)d_in[6];
    const float* b2  = (const float*)d_in[7];
    const float* Wp  = (const float*)d_in[8];
    const float* bp  = (const float*)d_in[9];
    float* out       = (float*)d_out;

    // workspace layout (bf16 activations first: 16B-aligned base)
    u16*  xA     = (u16*)d_ws;                    // N*HID bf16
    u16*  xB     = xA + (size_t)N * HID;          // N*HID bf16
    int2* packed = (int2*)(xB + (size_t)N * HID); // E int2 (offset 51.2MB, 16B-aligned)
    int*  cnt_i  = (int*)(packed + E);            // N
    int*  rowptr = cnt_i + N;                     // N+1
    int*  cursor = rowptr + N + 1;                // N
    int*  partial= cursor + N;                    // 256
    float* dinv  = (float*)(partial + 256);       // N
    float* pooled= dinv + N;                      // NG*HID
    float* cntg  = pooled + NG * HID;             // NG

    auto cdiv = [](int a, int b) { return (a + b - 1) / b; };
    int B = cdiv(N, SCHUNK);                      // 196 <= 256

    hipMemsetAsync(cnt_i, 0, N * sizeof(int), stream);
    hipMemsetAsync(pooled, 0, (NG * HID + NG) * sizeof(float), stream);

    // CSR build + normalization (multi-block scan)
    k_hist<<<cdiv(E, 256), 256, 0, stream>>>(dstp, cnt_i, E);
    k_scan1<<<B, 256, 0, stream>>>(cnt_i, partial, N);
    k_scan2<<<1, 256, 0, stream>>>(partial, B);
    k_scan3<<<B, 256, 0, stream>>>(cnt_i, partial, rowptr, dinv, N);
    hipMemcpyAsync(cursor, rowptr, N * sizeof(int), hipMemcpyDeviceToDevice, stream);
    k_fillcsr<<<cdiv(E, 256), 256, 0, stream>>>(src, dstp, dinv, cursor, packed, E);

    // layer 0 (rank-1 shortcut, fused S-reduce)
    k_sl0<<<cdiv(N, 8), 256, 0, stream>>>(rowptr, packed, dinv, W0, b0, xA, N);

    // layer 1
    k_gemm<<<cdiv(N, 32), 256, 0, stream>>>(xA, W1, xB, N);
    k_aggr<<<cdiv(N, 8), 256, 0, stream>>>(packed, rowptr, xB, dinv, b1, xA, N);

    // layer 2
    k_gemm<<<cdiv(N, 32), 256, 0, stream>>>(xA, W2, xB, N);
    k_aggr<<<cdiv(N, 8), 256, 0, stream>>>(packed, rowptr, xB, dinv, b2, xA, N);

    // pooling + head
    k_pool<<<cdiv(cdiv(N, 32), 2), 256, 0, stream>>>(xA, batch, pooled, cntg, N);
    k_head<<<2, 256, 0, stream>>>(pooled, cntg, Wp, bp, out);
}

// Round 4
// 382.803 us; speedup vs baseline: 5.1835x; 1.5111x over previous
//
#include <hip/hip_runtime.h>

#define HID 128
#define NG 512
#define NC 10
#define SCHUNK 512

typedef unsigned int u32;
typedef unsigned short u16;
typedef __attribute__((ext_vector_type(8))) short short8;
typedef __attribute__((ext_vector_type(4))) float f32x4;

static __device__ __forceinline__ int gtid() {
    return blockIdx.x * blockDim.x + threadIdx.x;
}

// bf16 helpers (RNE pack, exact unpack)
static __device__ __forceinline__ u16 f2bf(float f) {
    u32 u = __float_as_uint(f);
    u32 r = u + 0x7fffu + ((u >> 16) & 1u);
    return (u16)(r >> 16);
}
static __device__ __forceinline__ float bf2f(u32 s) {
    return __uint_as_float(s << 16);
}

// ---------- CSR build ----------

__global__ void k_hist(const int* __restrict__ dst, int* __restrict__ cnt, int E) {
    int i = gtid();
    if (i < E) atomicAdd(&cnt[dst[i]], 1);
}

__global__ __launch_bounds__(256) void k_scan1(const int* __restrict__ cnt,
                                               int* __restrict__ partial, int N) {
    __shared__ int s[256];
    int t = threadIdx.x;
    int i0 = blockIdx.x * SCHUNK + t * 2;
    int v = 0;
    if (i0 < N) v += cnt[i0];
    if (i0 + 1 < N) v += cnt[i0 + 1];
    s[t] = v;
    __syncthreads();
    for (int off = 128; off > 0; off >>= 1) {
        if (t < off) s[t] += s[t + off];
        __syncthreads();
    }
    if (t == 0) partial[blockIdx.x] = s[0];
}

__global__ __launch_bounds__(256) void k_scan2(int* __restrict__ partial, int B) {
    __shared__ int s[256];
    int t = threadIdx.x;
    int own = (t < B) ? partial[t] : 0;
    s[t] = own;
    __syncthreads();
    for (int off = 1; off < 256; off <<= 1) {
        int v = (t >= off) ? s[t - off] : 0;
        __syncthreads();
        s[t] += v;
        __syncthreads();
    }
    if (t < B) partial[t] = s[t] - own;  // exclusive
}

__global__ __launch_bounds__(256) void k_scan3(const int* __restrict__ cnt,
                                               const int* __restrict__ partial,
                                               int* __restrict__ rowptr,
                                               float* __restrict__ dinv, int N) {
    __shared__ int s[256];
    int t = threadIdx.x;
    int i0 = blockIdx.x * SCHUNK + t * 2;
    int c0 = 0, c1 = 0;
    if (i0 < N) c0 = cnt[i0];
    if (i0 + 1 < N) c1 = cnt[i0 + 1];
    int own = c0 + c1;
    s[t] = own;
    __syncthreads();
    for (int off = 1; off < 256; off <<= 1) {
        int v = (t >= off) ? s[t - off] : 0;
        __syncthreads();
        s[t] += v;
        __syncthreads();
    }
    int base = partial[blockIdx.x] + s[t] - own;
    if (i0 < N) { rowptr[i0] = base; dinv[i0] = rsqrtf(1.0f + (float)c0); }
    if (i0 + 1 < N) { rowptr[i0 + 1] = base + c0; dinv[i0 + 1] = rsqrtf(1.0f + (float)c1); }
    if (i0 >= N - 2 && i0 < N) rowptr[N] = base + own;
}

__global__ void k_fillcsr(const int* __restrict__ src, const int* __restrict__ dst,
                          const float* __restrict__ dinv, int* __restrict__ cursor,
                          int2* __restrict__ packed, int E) {
    int e = gtid();
    if (e < E) {
        int t = dst[e], s = src[e];
        int pos = atomicAdd(&cursor[t], 1);
        packed[pos] = make_int2(s, __float_as_int(dinv[s] * dinv[t]));
    }
}

// ---------- W -> bf16 transposed + XOR-swizzled (one-shot) ----------
// Wt row n holds W[:,n] over k, as 16 blocks of 8 bf16; block j stored at j^(n&7)
__global__ __launch_bounds__(256) void k_wt(const float* __restrict__ W,
                                            u16* __restrict__ Wt) {
    int t = gtid();               // 0..2047
    if (t >= 2048) return;
    int n = t >> 4;               // output row (col of W)
    int j = t & 15;               // 16B block index along k
    int js = j ^ (n & 7);
    u32 w0 = (u32)f2bf(W[(j * 8 + 0) * HID + n]) | ((u32)f2bf(W[(j * 8 + 1) * HID + n]) << 16);
    u32 w1 = (u32)f2bf(W[(j * 8 + 2) * HID + n]) | ((u32)f2bf(W[(j * 8 + 3) * HID + n]) << 16);
    u32 w2 = (u32)f2bf(W[(j * 8 + 4) * HID + n]) | ((u32)f2bf(W[(j * 8 + 5) * HID + n]) << 16);
    u32 w3 = (u32)f2bf(W[(j * 8 + 6) * HID + n]) | ((u32)f2bf(W[(j * 8 + 7) * HID + n]) << 16);
    uint4 o = make_uint4(w0, w1, w2, w3);
    *(uint4*)&Wt[(size_t)n * HID + js * 8] = o;
}

// ---------- layer 0 (rank-1 shortcut) ----------
__global__ __launch_bounds__(256) void k_sl0(const int* __restrict__ rowptr,
                                             const int2* __restrict__ packed,
                                             const float* __restrict__ dinv,
                                             const float* __restrict__ W0,
                                             const float* __restrict__ b0,
                                             u16* __restrict__ x, int N) {
    int lane = threadIdx.x & 31;
    int v = (blockIdx.x * 256 + threadIdx.x) >> 5;
    if (v >= N) return;
    int r0 = rowptr[v], r1 = rowptr[v + 1];
    float s = 0.0f;
    for (int j = r0 + lane; j < r1; j += 32) s += __int_as_float(packed[j].y);
#pragma unroll
    for (int off = 16; off > 0; off >>= 1) s += __shfl_xor(s, off, 32);
    float di = dinv[v];
    s += di * di;
    int d0 = lane * 4;
    float4 w = *(const float4*)&W0[d0];
    float4 b = *(const float4*)&b0[d0];
    float a0 = fmaxf(fmaf(s, w.x, b.x), 0.0f);
    float a1 = fmaxf(fmaf(s, w.y, b.y), 0.0f);
    float a2 = fmaxf(fmaf(s, w.z, b.z), 0.0f);
    float a3 = fmaxf(fmaf(s, w.w, b.w), 0.0f);
    uint2 o;
    o.x = (u32)f2bf(a0) | ((u32)f2bf(a1) << 16);
    o.y = (u32)f2bf(a2) | ((u32)f2bf(a3) << 16);
    *(uint2*)&x[(size_t)v * HID + d0] = o;
}

// ---------- MFMA GEMM: y[N,128] = x[N,128] @ W[128,128], bf16 in/out, fp32 accum ----------
// 64 rows/block, 4 waves; Wt (pre-transposed/swizzled bf16) staged to 32KB LDS.
__global__ __launch_bounds__(256) void k_gemm(const u16* __restrict__ x,
                                              const u16* __restrict__ Wt,
                                              u16* __restrict__ y, int nrows) {
    __shared__ u16 Wl[HID * HID];  // 32 KiB
    int tid = threadIdx.x;
    for (int i = tid; i < 2048; i += 256)
        *(uint4*)&Wl[i * 8] = *(const uint4*)&Wt[i * 8];

    int w = tid >> 6;
    int l = tid & 63;
    int R0 = blockIdx.x * 64 + w * 16;
    int arow = R0 + (l & 15);
    int koff = (l >> 4) * 8;

    short8 a[4];
#pragma unroll
    for (int kb = 0; kb < 4; ++kb) {
        if (arow < nrows)
            a[kb] = *(const short8*)&x[(size_t)arow * HID + kb * 32 + koff];
        else
            a[kb] = (short8)0;
    }
    __syncthreads();

    int colbase = l & 15;
    int rowq = (l >> 4) * 4;
#pragma unroll
    for (int cb = 0; cb < 8; ++cb) {
        f32x4 acc = {0.0f, 0.0f, 0.0f, 0.0f};
        int wrow = cb * 16 + (l & 15);
#pragma unroll
        for (int kb = 0; kb < 4; ++kb) {
            int j = (kb * 4 + (l >> 4)) ^ (wrow & 7);
            short8 b = *(const short8*)&Wl[wrow * HID + j * 8];
            acc = __builtin_amdgcn_mfma_f32_16x16x32_bf16(a[kb], b, acc, 0, 0, 0);
        }
#pragma unroll
        for (int i = 0; i < 4; ++i) {
            int orow = R0 + rowq + i;
            if (orow < nrows)
                y[(size_t)orow * HID + cb * 16 + colbase] = f2bf(acc[i]);
        }
    }
}

// ---------- fused aggregation ----------
__global__ __launch_bounds__(256) void k_aggr(const int2* __restrict__ packed,
                                              const int* __restrict__ rowptr,
                                              const u16* __restrict__ h,
                                              const float* __restrict__ dinv,
                                              const float* __restrict__ b,
                                              u16* __restrict__ y, int N) {
    int lane = threadIdx.x & 31;
    int v = (blockIdx.x * 256 + threadIdx.x) >> 5;
    if (v >= N) return;
    int r0 = rowptr[v], r1 = rowptr[v + 1];
    float di = dinv[v];
    float d2 = di * di;
    int d0 = lane * 4;
    uint2 hu = *(const uint2*)&h[(size_t)v * HID + d0];
    float4 bv = *(const float4*)&b[d0];
    float a0 = fmaf(bf2f(hu.x & 0xffffu), d2, bv.x);
    float a1 = fmaf(bf2f(hu.x >> 16),     d2, bv.y);
    float a2 = fmaf(bf2f(hu.y & 0xffffu), d2, bv.z);
    float a3 = fmaf(bf2f(hu.y >> 16),     d2, bv.w);
    for (int base = r0; base < r1; base += 32) {
        int2 pk = (base + lane < r1) ? packed[base + lane] : make_int2(0, 0);
        int m = r1 - base; if (m > 32) m = 32;
        for (int k = 0; k < m; ++k) {
            int s = __shfl(pk.x, k, 32);
            float nv = __shfl(__int_as_float(pk.y), k, 32);
            uint2 hs = *(const uint2*)&h[(size_t)s * HID + d0];
            a0 = fmaf(bf2f(hs.x & 0xffffu), nv, a0);
            a1 = fmaf(bf2f(hs.x >> 16),     nv, a1);
            a2 = fmaf(bf2f(hs.y & 0xffffu), nv, a2);
            a3 = fmaf(bf2f(hs.y >> 16),     nv, a3);
        }
    }
    uint2 o;
    o.x = (u32)f2bf(fmaxf(a0, 0.0f)) | ((u32)f2bf(fmaxf(a1, 0.0f)) << 16);
    o.y = (u32)f2bf(fmaxf(a2, 0.0f)) | ((u32)f2bf(fmaxf(a3, 0.0f)) << 16);
    *(uint2*)&y[(size_t)v * HID + d0] = o;
}

// ---------- pooling + head ----------

__global__ void k_pool(const u16* __restrict__ x, const int* __restrict__ batch,
                       float* __restrict__ pooled, float* __restrict__ cnt, int N) {
    const int K = 32;
    int d = threadIdx.x & (HID - 1);
    int chunk = blockIdx.x * 2 + (threadIdx.x >> 7);
    int v0 = chunk * K;
    if (v0 >= N) return;
    int vend = v0 + K; if (vend > N) vend = N;
    int g = batch[v0];
    float acc = 0.0f, c = 0.0f;
    for (int v = v0; v < vend; ++v) {
        int gv = batch[v];
        if (gv != g) {
            atomicAdd(&pooled[g * HID + d], acc);
            if (d == 0) atomicAdd(&cnt[g], c);
            acc = 0.0f; c = 0.0f; g = gv;
        }
        acc += bf2f((u32)x[(size_t)v * HID + d]);
        c += 1.0f;
    }
    atomicAdd(&pooled[g * HID + d], acc);
    if (d == 0) atomicAdd(&cnt[g], c);
}

__global__ void k_head(const float* __restrict__ pooled, const float* __restrict__ cnt,
                       const float* __restrict__ Wp, const float* __restrict__ bp,
                       float* __restrict__ out) {
    int g = gtid();
    if (g >= NG) return;
    float inv = 1.0f / fmaxf(cnt[g], 1.0f);
    float l[NC];
#pragma unroll
    for (int c = 0; c < NC; ++c) l[c] = bp[c];
    for (int d = 0; d < HID; ++d) {
        float pv = pooled[g * HID + d] * inv;
#pragma unroll
        for (int c = 0; c < NC; ++c) l[c] = fmaf(pv, Wp[d * NC + c], l[c]);
    }
    float m = l[0];
#pragma unroll
    for (int c = 1; c < NC; ++c) m = fmaxf(m, l[c]);
    float s = 0.0f;
#pragma unroll
    for (int c = 0; c < NC; ++c) s += expf(l[c] - m);
    float ls = logf(s) + m;
#pragma unroll
    for (int c = 0; c < NC; ++c) out[g * NC + c] = l[c] - ls;
}

extern "C" void kernel_launch(void* const* d_in, const int* in_sizes, int n_in,
                              void* d_out, int out_size, void* d_ws, size_t ws_size,
                              hipStream_t stream) {
    const int* ei    = (const int*)d_in[0];
    int E            = in_sizes[0] / 2;
    const int* src   = ei;
    const int* dstp  = ei + E;
    const int* batch = (const int*)d_in[1];
    int N            = in_sizes[1];
    const float* W0  = (const float*)d_in[2];
    const float* b0  = (const float*)d_in[3];
    const float* W1  = (const float*)d_in[4];
    const float* b1  = (const float*)d_in[5];
    const float* W2  = (const float*)d_in[6];
    const float* b2  = (const float*)d_in[7];
    const float* Wp  = (const float*)d_in[8];
    const float* bp  = (const float*)d_in[9];
    float* out       = (float*)d_out;

    // workspace layout
    u16*  xA     = (u16*)d_ws;                    // N*HID bf16
    u16*  xB     = xA + (size_t)N * HID;          // N*HID bf16
    int2* packed = (int2*)(xB + (size_t)N * HID); // E int2
    u16*  Wt1    = (u16*)(packed + E);            // 128*128 bf16 (32KB)
    u16*  Wt2    = Wt1 + HID * HID;               // 128*128 bf16
    int*  cnt_i  = (int*)(Wt2 + HID * HID);       // N
    int*  rowptr = cnt_i + N;                     // N+1
    int*  cursor = rowptr + N + 1;                // N
    int*  partial= cursor + N;                    // 256
    float* dinv  = (float*)(partial + 256);       // N
    float* pooled= dinv + N;                      // NG*HID
    float* cntg  = pooled + NG * HID;             // NG

    auto cdiv = [](int a, int b) { return (a + b - 1) / b; };
    int B = cdiv(N, SCHUNK);

    hipMemsetAsync(cnt_i, 0, N * sizeof(int), stream);
    hipMemsetAsync(pooled, 0, (NG * HID + NG) * sizeof(float), stream);

    // CSR build + normalization
    k_hist<<<cdiv(E, 256), 256, 0, stream>>>(dstp, cnt_i, E);
    k_scan1<<<B, 256, 0, stream>>>(cnt_i, partial, N);
    k_scan2<<<1, 256, 0, stream>>>(partial, B);
    k_scan3<<<B, 256, 0, stream>>>(cnt_i, partial, rowptr, dinv, N);
    hipMemcpyAsync(cursor, rowptr, N * sizeof(int), hipMemcpyDeviceToDevice, stream);
    k_fillcsr<<<cdiv(E, 256), 256, 0, stream>>>(src, dstp, dinv, cursor, packed, E);

    // weight prep (bf16, transposed, swizzled)
    k_wt<<<8, 256, 0, stream>>>(W1, Wt1);
    k_wt<<<8, 256, 0, stream>>>(W2, Wt2);

    // layer 0 (rank-1 shortcut)
    k_sl0<<<cdiv(N, 8), 256, 0, stream>>>(rowptr, packed, dinv, W0, b0, xA, N);

    // layer 1
    k_gemm<<<cdiv(N, 64), 256, 0, stream>>>(xA, Wt1, xB, N);
    k_aggr<<<cdiv(N, 8), 256, 0, stream>>>(packed, rowptr, xB, dinv, b1, xA, N);

    // layer 2
    k_gemm<<<cdiv(N, 64), 256, 0, stream>>>(xA, Wt2, xB, N);
    k_aggr<<<cdiv(N, 8), 256, 0, stream>>>(packed, rowptr, xB, dinv, b2, xA, N);

    // pooling + head
    k_pool<<<cdiv(cdiv(N, 32), 2), 256, 0, stream>>>(xA, batch, pooled, cntg, N);
    k_head<<<2, 256, 0, stream>>>(pooled, cntg, Wp, bp, out);
}